// Round 13
// baseline (438.229 us; speedup 1.0000x reference)
//
#include <hip/hip_runtime.h>

// NT-Xent loss: z_i, z_j [4096,1024] f32 -> scalar f32 loss.
// loss = mean_i( log(sum_{j != i} exp(2*cos_sim(i,j))) - 2*cos_sim(i, i^1) )
//
// R13: R12 + 2-ahead staging (T4 counted vmcnt) re-attempted with fully
//      LITERAL addressing: 6 named __shared__ arrays (A0/A1/A2, B0/B1/B2),
//      16 explicitly instantiated K-bodies (no runtime slot arithmetic),
//      R11 body order {reads -> stage(kt+2) -> MFMA -> vmcnt(6) -> barrier}.
//      stage(kt+1) now has a full K-body (~2600 cy) of flight cover instead
//      of an 8-MFMA window. Kernels 1/3/4 unchanged from R12.

#define N_ROWS 8192
#define HALF_N 4096
#define DIMK   1024
#define KTILES 16          // 1024 / 64
#define NJC    64          // 128-wide column panels
#define NTILES 1056        // sum_{jc} (jc/2 + 1)
#define LOGIT_SCALE (2.0f / 256.0f)   // /TEMPERATURE, undo 16*16 fp8 pre-scale

typedef float        f32x16 __attribute__((ext_vector_type(16)));
typedef int          i32x8  __attribute__((ext_vector_type(8)));
typedef unsigned int u32x4  __attribute__((ext_vector_type(4)));

// ---------------- fp8 e4m3 (OCP) conversion ---------------------------------
__device__ __forceinline__ unsigned int f32_to_e4m3_sw(float f) {
    unsigned int b = __float_as_uint(f);
    unsigned int s = (b >> 24) & 0x80u;
    float a = fabsf(f);
    if (a < 0.0009765625f) return s;
    if (a < 0.015625f) {
        int q = (int)rintf(a * 512.0f);
        return s | (unsigned int)q;
    }
    if (a >= 464.0f) return s | 0x7Eu;
    int e = (int)((b >> 23) & 0xFF) - 127;
    unsigned int man = b & 0x7FFFFFu;
    unsigned int r = man + 0x7FFFFu + ((man >> 20) & 1u);
    unsigned int m8 = r >> 20;
    if (m8 == 8u) { m8 = 0u; ++e; if (e > 8) return s | 0x7Eu; }
    return s | ((unsigned int)(e + 7) << 3) | m8;
}

__device__ __forceinline__ unsigned int pack4_e4m3(float x, float y,
                                                   float z, float w) {
#if __has_builtin(__builtin_amdgcn_cvt_pk_fp8_f32)
    int p = __builtin_amdgcn_cvt_pk_fp8_f32(x, y, 0, false);   // low word
    p     = __builtin_amdgcn_cvt_pk_fp8_f32(z, w, p, true);    // high word
    return (unsigned int)p;
#else
    return f32_to_e4m3_sw(x) | (f32_to_e4m3_sw(y) << 8)
         | (f32_to_e4m3_sw(z) << 16) | (f32_to_e4m3_sw(w) << 24);
#endif
}

// ---------------- Kernel 1: row L2-normalize, f32 -> fp8*16 ------------------
__global__ __launch_bounds__(256) void norm_rows_kernel(
    const float* __restrict__ z_i, const float* __restrict__ z_j,
    unsigned int* __restrict__ xn8)   // [8192][256] u32 (=1024 fp8)
{
    const int wave = threadIdx.x >> 6, lane = threadIdx.x & 63;
    const int row = blockIdx.x * 4 + wave;
    const float* src = (row < HALF_N) ? (z_i + (size_t)row * DIMK)
                                      : (z_j + (size_t)(row - HALF_N) * DIMK);
    float4 v[4];
    float ss = 0.0f;
    #pragma unroll
    for (int i = 0; i < 4; ++i) {
        v[i] = ((const float4*)src)[i * 64 + lane];
        ss += v[i].x * v[i].x + v[i].y * v[i].y + v[i].z * v[i].z + v[i].w * v[i].w;
    }
    #pragma unroll
    for (int m = 1; m < 64; m <<= 1) ss += __shfl_xor(ss, m, 64);
    const float rn = 16.0f / fmaxf(sqrtf(ss), 1e-8f);   // x16 fp8 pre-scale

    unsigned int* dst = xn8 + (size_t)row * (DIMK / 4);
    #pragma unroll
    for (int i = 0; i < 4; ++i)
        dst[i * 64 + lane] = pack4_e4m3(v[i].x * rn, v[i].y * rn,
                                        v[i].z * rn, v[i].w * rn);
}

// ---- Kernel 2: fused sim-GEMM (MX-fp8 32x32x64) + exp row/col sums ----------
#define BAR() do { asm volatile("" ::: "memory"); \
                   __builtin_amdgcn_s_barrier();  \
                   asm volatile("" ::: "memory"); } while (0)
#define WAITVM6() asm volatile("s_waitcnt vmcnt(6)" ::: "memory")
#define WAITVM0() asm volatile("s_waitcnt vmcnt(0)" ::: "memory")
#define GLDS(gp, lp) __builtin_amdgcn_global_load_lds(                          \
        (const __attribute__((address_space(1))) void*)(gp),                    \
        (__attribute__((address_space(3))) void*)(lp), 16, 0, 0)

// LDS placement (R9): pair two 64-B rows into a 128-B window, XOR chunk pos:
// unit(r,c) = (r>>1)*8 + ((((r&1)<<2)|c) ^ ((r>>1)&7)). Bijective; frag reads
// phase-uniform; GLDS sources = 64-B coalesced segments.
__device__ __forceinline__ int unit_of(int r, int c) {
    return ((r >> 1) << 3) + (((((r & 1) << 2) | c)) ^ ((r >> 1) & 7));
}

__global__ __launch_bounds__(256, 2) void simexp_kernel(
    const unsigned char* __restrict__ xn8,
    float* __restrict__ rs,     // [128][N_ROWS] planes: jc*2 + wn
    float* __restrict__ cs,     // [64][N_ROWS]  planes: rt*2 + wm
    float* __restrict__ tgt)    // [N_ROWS]
{
    __shared__ u32x4 A0[1024], A1[1024], A2[1024];   // 3 x 16 KiB
    __shared__ u32x4 B0[512],  B1[512],  B2[512];    // 3 x  8 KiB

    // bijective XCD swizzle: 1056 = 8 * 132
    const int orig = blockIdx.x;
    const int bid  = (orig & 7) * 132 + (orig >> 3);

    // decode (rt, jc): tiles ordered jc-major, rt = 0..jc/2
    int rem = bid, jc = 0;
    for (;;) { const int cnt = (jc >> 1) + 1; if (rem < cnt) break; rem -= cnt; ++jc; }
    const int rt = rem;

    const int t = threadIdx.x;
    const int lane = t & 63, wave = t >> 6;
    const int wm = wave >> 1, wn = wave & 1;     // 2x2 wave grid
    const int rowBase = rt * 256, colBase = jc * 128;
    const int l31 = lane & 31, h = lane >> 5;

    f32x16 acc[4][2];
    #pragma unroll
    for (int i = 0; i < 4; ++i)
        #pragma unroll
        for (int j = 0; j < 2; ++j)
            #pragma unroll
            for (int v = 0; v < 16; ++v) acc[i][j][v] = 0.0f;

    // staging: unit u = s_*256 + t (linear LDS dest); inverse map:
    // r2 = u>>3, y = (u&7) ^ (r2&7), row = 2*r2 + (y>>2), chunk = y&3.
#define STAGE_TILE(AW, BW, KT) do {                                              \
        _Pragma("unroll")                                                        \
        for (int s_ = 0; s_ < 4; ++s_) {                                         \
            const int u_  = s_ * 256 + t;                                        \
            const int r2_ = u_ >> 3;                                             \
            const int y_  = (u_ & 7) ^ (r2_ & 7);                                \
            const int rl_ = 2 * r2_ + (y_ >> 2);                                 \
            const unsigned char* g = xn8 +                                       \
                (size_t)(rowBase + rl_) * DIMK + (KT) * 64 + (y_ & 3) * 16;      \
            GLDS(g, &AW[s_ * 256 + wave * 64]);                                  \
        }                                                                        \
        _Pragma("unroll")                                                        \
        for (int s_ = 0; s_ < 2; ++s_) {                                         \
            const int u_  = s_ * 256 + t;                                        \
            const int r2_ = u_ >> 3;                                             \
            const int y_  = (u_ & 7) ^ (r2_ & 7);                                \
            const int rl_ = 2 * r2_ + (y_ >> 2);                                 \
            const unsigned char* g = xn8 +                                       \
                (size_t)(colBase + rl_) * DIMK + (KT) * 64 + (y_ & 3) * 16;      \
            GLDS(g, &BW[s_ * 256 + wave * 64]);                                  \
        }                                                                        \
    } while (0)

    // one K-body: reads(AR,BR) -> [stage(AW,BW,KT2)] -> MFMA -> wait -> bar
#define K_READS(AR, BR)                                                          \
        union Frag { u32x4 q[2]; i32x8 v; };                                     \
        i32x8 af[4], bf[2];                                                      \
        _Pragma("unroll")                                                        \
        for (int fi = 0; fi < 4; ++fi) {                                         \
            const int r = wm * 128 + fi * 32 + l31;                              \
            Frag fa;                                                             \
            fa.q[0] = AR[unit_of(r, 2 * h)];                                     \
            fa.q[1] = AR[unit_of(r, 2 * h + 1)];                                 \
            af[fi] = fa.v;                                                       \
        }                                                                        \
        _Pragma("unroll")                                                        \
        for (int cf = 0; cf < 2; ++cf) {                                         \
            const int r = wn * 64 + cf * 32 + l31;                               \
            Frag fb;                                                             \
            fb.q[0] = BR[unit_of(r, 2 * h)];                                     \
            fb.q[1] = BR[unit_of(r, 2 * h + 1)];                                 \
            bf[cf] = fb.v;                                                       \
        }
#define K_MFMA()                                                                 \
        __builtin_amdgcn_s_setprio(1);                                           \
        _Pragma("unroll")                                                        \
        for (int fi = 0; fi < 4; ++fi)                                           \
            _Pragma("unroll")                                                    \
            for (int cf = 0; cf < 2; ++cf)                                       \
                acc[fi][cf] = __builtin_amdgcn_mfma_scale_f32_32x32x64_f8f6f4(   \
                    af[fi], bf[cf], acc[fi][cf], 0, 0,                           \
                    0, 0x7F7F7F7F, 0, 0x7F7F7F7F);                               \
        __builtin_amdgcn_s_setprio(0);

#define BODY_S(AR, BR, AW, BW, KT2) do {                                         \
        K_READS(AR, BR)                                                          \
        STAGE_TILE(AW, BW, KT2);                                                 \
        K_MFMA()                                                                 \
        WAITVM6();                                                               \
        BAR();                                                                   \
    } while (0)
#define BODY_W0(AR, BR) do {                                                     \
        K_READS(AR, BR)                                                          \
        K_MFMA()                                                                 \
        WAITVM0();                                                               \
        BAR();                                                                   \
    } while (0)
#define BODY_END(AR, BR) do {                                                    \
        K_READS(AR, BR)                                                          \
        K_MFMA()                                                                 \
    } while (0)

    // prologue: stage kt0 -> slot0, kt1 -> slot1; drain kt0 only (6 left)
    STAGE_TILE(A0, B0, 0);
    STAGE_TILE(A1, B1, 1);
    WAITVM6();
    BAR();

    // kt = 0..13: read slot kt%3, stage kt+2 into slot (kt+2)%3
    BODY_S(A0, B0, A2, B2, 2);    // kt 0
    BODY_S(A1, B1, A0, B0, 3);    // kt 1
    BODY_S(A2, B2, A1, B1, 4);    // kt 2
    BODY_S(A0, B0, A2, B2, 5);    // kt 3
    BODY_S(A1, B1, A0, B0, 6);    // kt 4
    BODY_S(A2, B2, A1, B1, 7);    // kt 5
    BODY_S(A0, B0, A2, B2, 8);    // kt 6
    BODY_S(A1, B1, A0, B0, 9);    // kt 7
    BODY_S(A2, B2, A1, B1, 10);   // kt 8
    BODY_S(A0, B0, A2, B2, 11);   // kt 9
    BODY_S(A1, B1, A0, B0, 12);   // kt 10
    BODY_S(A2, B2, A1, B1, 13);   // kt 11
    BODY_S(A0, B0, A2, B2, 14);   // kt 12
    BODY_S(A1, B1, A0, B0, 15);   // kt 13
    BODY_W0(A2, B2);              // kt 14: drain stage(15)
    BODY_END(A0, B0);             // kt 15: compute only
#undef STAGE_TILE
#undef K_READS
#undef K_MFMA
#undef BODY_S
#undef BODY_W0
#undef BODY_END

    // ---- epilogue ----
    // C/D 32x32 layout (m74/m101): col = lane&31, row = (v&3)+8*(v>>2)+4*(lane>>5)
    float cspart[2] = {0.0f, 0.0f};
    #pragma unroll
    for (int fi = 0; fi < 4; ++fi) {
        float rpart[16];
        #pragma unroll
        for (int v = 0; v < 16; ++v) rpart[v] = 0.0f;
        #pragma unroll
        for (int cf = 0; cf < 2; ++cf) {
            const int gcol = colBase + wn * 64 + cf * 32 + l31;
            #pragma unroll
            for (int v = 0; v < 16; ++v) {
                const int grow = rowBase + wm * 128 + fi * 32
                               + (v & 3) + 8 * (v >> 2) + 4 * h;
                const float tv = acc[fi][cf][v] * LOGIT_SCALE;
                if (gcol == grow + 1 && ((grow & 1) == 0)) {
                    tgt[grow] = tv; tgt[grow + 1] = tv;   // sim symmetric
                }
                const float ev = (gcol > grow) ? __expf(tv) : 0.0f;
                rpart[v] += ev;
                cspart[cf] += ev;
            }
        }
        // row sums: reduce over the 32 columns (lanes sharing l>>5)
        #pragma unroll
        for (int m = 1; m < 32; m <<= 1) {
            #pragma unroll
            for (int v = 0; v < 16; ++v) rpart[v] += __shfl_xor(rpart[v], m, 64);
        }
        if (l31 == 0) {
            float* dst = rs + (size_t)(jc * 2 + wn) * N_ROWS;
            #pragma unroll
            for (int v = 0; v < 16; ++v)
                dst[rowBase + wm * 128 + fi * 32 + (v & 3) + 8 * (v >> 2) + 4 * h]
                    = rpart[v];
        }
    }
    // column sums (mirror): combine lane halves, lanes 0-31 write
    #pragma unroll
    for (int cf = 0; cf < 2; ++cf) {
        cspart[cf] += __shfl_xor(cspart[cf], 32, 64);
        if (lane < 32)
            cs[(size_t)(rt * 2 + wm) * N_ROWS + colBase + wn * 64 + cf * 32 + l31]
                = cspart[cf];
    }
}

// ------------- Kernel 3: per-row LSE - target logit --------------------------
__global__ __launch_bounds__(256) void row_term_kernel(
    const float* __restrict__ rs, const float* __restrict__ cs,
    const float* __restrict__ tgt, float* __restrict__ terms)
{
    const int row = blockIdx.x * 256 + threadIdx.x;
    const int P = row >> 8, jcx = row >> 7;
    float s = 0.0f;
    for (int jc = 2 * P; jc < NJC; ++jc) {
        const float* b = rs + (size_t)(jc * 2) * N_ROWS + row;
        s += b[0] + b[N_ROWS];
    }
    for (int rt = 0; rt <= (jcx >> 1); ++rt) {
        const float* b = cs + (size_t)(rt * 2) * N_ROWS + row;
        s += b[0] + b[N_ROWS];
    }
    terms[row] = logf(s) - tgt[row];
}

// ------------- Kernel 4: mean over rows --------------------------------------
__global__ __launch_bounds__(1024) void loss_kernel(
    const float* __restrict__ terms, float* __restrict__ out)
{
    const int t = threadIdx.x;
    float s = 0.0f;
    for (int i = t; i < N_ROWS; i += 1024) s += terms[i];
    #pragma unroll
    for (int m = 1; m < 64; m <<= 1) s += __shfl_xor(s, m, 64);
    __shared__ float red[16];
    if ((t & 63) == 0) red[t >> 6] = s;
    __syncthreads();
    if (t == 0) {
        float tot = 0.0f;
        #pragma unroll
        for (int i = 0; i < 16; ++i) tot += red[i];
        out[0] = tot * (1.0f / N_ROWS);
    }
}

extern "C" void kernel_launch(void* const* d_in, const int* in_sizes, int n_in,
                              void* d_out, int out_size, void* d_ws, size_t ws_size,
                              hipStream_t stream)
{
    const float* z_i = (const float*)d_in[0];
    const float* z_j = (const float*)d_in[1];
    float* out = (float*)d_out;

    // workspace layout
    unsigned char* xn8 = (unsigned char*)d_ws;                        // 8 MiB fp8
    float* rs    = (float*)(xn8 + (size_t)N_ROWS * DIMK);             // 4 MiB
    float* cs    = rs + (size_t)128 * N_ROWS;                         // 2 MiB
    float* tgt   = cs + (size_t)64 * N_ROWS;                          // 32 KiB
    float* terms = tgt + N_ROWS;                                      // 32 KiB

    norm_rows_kernel<<<N_ROWS / 4, 256, 0, stream>>>(z_i, z_j, (unsigned int*)xn8);
    simexp_kernel<<<NTILES, 256, 0, stream>>>(xn8, rs, cs, tgt);
    row_term_kernel<<<N_ROWS / 256, 256, 0, stream>>>(rs, cs, tgt, terms);
    loss_kernel<<<1, 1024, 0, stream>>>(terms, out);
}

// Round 14
// 99.383 us; speedup vs baseline: 4.4095x; 4.4095x over previous
//
#include <hip/hip_runtime.h>

// NT-Xent loss: z_i, z_j [4096,1024] f32 -> scalar f32 loss.
// loss = mean_i( log(sum_{j != i} exp(2*cos_sim(i,j))) - 2*cos_sim(i, i^1) )
//
// R14: 256x256 tiles, 512 thr (8 waves, 2x4), 2 slots x (A 16KB + B 16KB) =
//      64 KiB LDS, 1 block/CU. Per-wave state BYTE-IDENTICAL to the clean
//      R12 shape (acc[4][2] f32x16 -> AGPRs, af[4], bf[2]); body order R11
//      {reads -> stage(kt+1) -> MFMA -> vmcnt(0) -> barrier}. 528 triangle
//      blocks (8x66 XCD swizzle). Halves per-CU drain events (66 -> 33).

#define N_ROWS 8192
#define HALF_N 4096
#define DIMK   1024
#define KTILES 16          // 1024 / 64
#define NPANEL 32          // 256-row/col panels
#define NTILES 528         // 32*33/2
#define LOGIT_SCALE (2.0f / 256.0f)   // /TEMPERATURE, undo 16*16 fp8 pre-scale

typedef float        f32x16 __attribute__((ext_vector_type(16)));
typedef int          i32x8  __attribute__((ext_vector_type(8)));
typedef unsigned int u32x4  __attribute__((ext_vector_type(4)));

// ---------------- fp8 e4m3 (OCP) conversion ---------------------------------
__device__ __forceinline__ unsigned int f32_to_e4m3_sw(float f) {
    unsigned int b = __float_as_uint(f);
    unsigned int s = (b >> 24) & 0x80u;
    float a = fabsf(f);
    if (a < 0.0009765625f) return s;
    if (a < 0.015625f) {
        int q = (int)rintf(a * 512.0f);
        return s | (unsigned int)q;
    }
    if (a >= 464.0f) return s | 0x7Eu;
    int e = (int)((b >> 23) & 0xFF) - 127;
    unsigned int man = b & 0x7FFFFFu;
    unsigned int r = man + 0x7FFFFu + ((man >> 20) & 1u);
    unsigned int m8 = r >> 20;
    if (m8 == 8u) { m8 = 0u; ++e; if (e > 8) return s | 0x7Eu; }
    return s | ((unsigned int)(e + 7) << 3) | m8;
}

__device__ __forceinline__ unsigned int pack4_e4m3(float x, float y,
                                                   float z, float w) {
#if __has_builtin(__builtin_amdgcn_cvt_pk_fp8_f32)
    int p = __builtin_amdgcn_cvt_pk_fp8_f32(x, y, 0, false);   // low word
    p     = __builtin_amdgcn_cvt_pk_fp8_f32(z, w, p, true);    // high word
    return (unsigned int)p;
#else
    return f32_to_e4m3_sw(x) | (f32_to_e4m3_sw(y) << 8)
         | (f32_to_e4m3_sw(z) << 16) | (f32_to_e4m3_sw(w) << 24);
#endif
}

// ---------------- Kernel 1: row L2-normalize, f32 -> fp8*16 ------------------
__global__ __launch_bounds__(256) void norm_rows_kernel(
    const float* __restrict__ z_i, const float* __restrict__ z_j,
    unsigned int* __restrict__ xn8)   // [8192][256] u32 (=1024 fp8)
{
    const int wave = threadIdx.x >> 6, lane = threadIdx.x & 63;
    const int row = blockIdx.x * 4 + wave;
    const float* src = (row < HALF_N) ? (z_i + (size_t)row * DIMK)
                                      : (z_j + (size_t)(row - HALF_N) * DIMK);
    float4 v[4];
    float ss = 0.0f;
    #pragma unroll
    for (int i = 0; i < 4; ++i) {
        v[i] = ((const float4*)src)[i * 64 + lane];
        ss += v[i].x * v[i].x + v[i].y * v[i].y + v[i].z * v[i].z + v[i].w * v[i].w;
    }
    #pragma unroll
    for (int m = 1; m < 64; m <<= 1) ss += __shfl_xor(ss, m, 64);
    const float rn = 16.0f / fmaxf(sqrtf(ss), 1e-8f);   // x16 fp8 pre-scale

    unsigned int* dst = xn8 + (size_t)row * (DIMK / 4);
    #pragma unroll
    for (int i = 0; i < 4; ++i)
        dst[i * 64 + lane] = pack4_e4m3(v[i].x * rn, v[i].y * rn,
                                        v[i].z * rn, v[i].w * rn);
}

// ---- Kernel 2: fused sim-GEMM (MX-fp8 32x32x64) + exp row/col sums ----------
#define BAR() do { asm volatile("" ::: "memory"); \
                   __builtin_amdgcn_s_barrier();  \
                   asm volatile("" ::: "memory"); } while (0)
#define WAITVM0() asm volatile("s_waitcnt vmcnt(0)" ::: "memory")
#define GLDS(gp, lp) __builtin_amdgcn_global_load_lds(                          \
        (const __attribute__((address_space(1))) void*)(gp),                    \
        (__attribute__((address_space(3))) void*)(lp), 16, 0, 0)

// LDS placement (R9): pair two 64-B rows into a 128-B window, XOR chunk pos:
// unit(r,c) = (r>>1)*8 + ((((r&1)<<2)|c) ^ ((r>>1)&7)). Bijective; frag reads
// phase-uniform; GLDS sources = 64-B coalesced segments.
__device__ __forceinline__ int unit_of(int r, int c) {
    return ((r >> 1) << 3) + (((((r & 1) << 2) | c)) ^ ((r >> 1) & 7));
}

__global__ __launch_bounds__(512, 1) void simexp_kernel(
    const unsigned char* __restrict__ xn8,
    float* __restrict__ rs,     // [128][N_ROWS] planes: jp*4 + wn
    float* __restrict__ cs,     // [64][N_ROWS]  planes: ip*2 + wm
    float* __restrict__ tgt)    // [N_ROWS]
{
    __shared__ u32x4 Abuf[2][1024];   // 2 x 16 KiB (256 rows x 4 chunks)
    __shared__ u32x4 Bbuf[2][1024];   // 2 x 16 KiB (256 cols x 4 chunks)

    // bijective XCD swizzle: 528 = 8 * 66
    const int orig = blockIdx.x;
    const int bid  = (orig & 7) * 66 + (orig >> 3);

    // decode (ip, jp), ip <= jp, over 32 panels
    int rem = bid, ip = 0;
    while (rem >= NPANEL - ip) { rem -= NPANEL - ip; ++ip; }
    const int jp = ip + rem;

    const int t = threadIdx.x;
    const int lane = t & 63, wave = t >> 6;
    const int wm = wave >> 2, wn = wave & 3;     // 2x4 wave grid, 128x64 each
    const int rowBase = ip * 256, colBase = jp * 256;
    const int l31 = lane & 31, h = lane >> 5;

    f32x16 acc[4][2];
    #pragma unroll
    for (int i = 0; i < 4; ++i)
        #pragma unroll
        for (int j = 0; j < 2; ++j)
            #pragma unroll
            for (int v = 0; v < 16; ++v) acc[i][j][v] = 0.0f;

    // staging: unit u = s_*512 + t (linear LDS dest); inverse map:
    // r2 = u>>3, y = (u&7) ^ (r2&7), row = 2*r2 + (y>>2), chunk = y&3.
#define STAGE_TILE(SLOT, KT) do {                                                \
        _Pragma("unroll")                                                        \
        for (int s_ = 0; s_ < 2; ++s_) {                                         \
            const int u_  = s_ * 512 + t;                                        \
            const int r2_ = u_ >> 3;                                             \
            const int y_  = (u_ & 7) ^ (r2_ & 7);                                \
            const int rl_ = 2 * r2_ + (y_ >> 2);                                 \
            const unsigned char* g = xn8 +                                       \
                (size_t)(rowBase + rl_) * DIMK + (KT) * 64 + (y_ & 3) * 16;      \
            GLDS(g, &Abuf[SLOT][s_ * 512 + wave * 64]);                          \
        }                                                                        \
        _Pragma("unroll")                                                        \
        for (int s_ = 0; s_ < 2; ++s_) {                                         \
            const int u_  = s_ * 512 + t;                                        \
            const int r2_ = u_ >> 3;                                             \
            const int y_  = (u_ & 7) ^ (r2_ & 7);                                \
            const int rl_ = 2 * r2_ + (y_ >> 2);                                 \
            const unsigned char* g = xn8 +                                       \
                (size_t)(colBase + rl_) * DIMK + (KT) * 64 + (y_ & 3) * 16;      \
            GLDS(g, &Bbuf[SLOT][s_ * 512 + wave * 64]);                          \
        }                                                                        \
    } while (0)

    // prologue: tile 0 into slot 0
    STAGE_TILE(0, 0);
    WAITVM0();
    BAR();

    int slot = 0;
    for (int kt = 0; kt < KTILES; ++kt) {
        const bool nx = (kt + 1 < KTILES);

        // ---- frag reads FIRST (vmcnt already 0 here -> no forced drain) ----
        union Frag { u32x4 q[2]; i32x8 v; };
        i32x8 af[4], bf[2];
        #pragma unroll
        for (int fi = 0; fi < 4; ++fi) {
            const int r = wm * 128 + fi * 32 + l31;
            Frag fa;
            fa.q[0] = Abuf[slot][unit_of(r, 2 * h)];
            fa.q[1] = Abuf[slot][unit_of(r, 2 * h + 1)];
            af[fi] = fa.v;
        }
        #pragma unroll
        for (int cf = 0; cf < 2; ++cf) {
            const int r = wn * 64 + cf * 32 + l31;
            Frag fb;
            fb.q[0] = Bbuf[slot][unit_of(r, 2 * h)];
            fb.q[1] = Bbuf[slot][unit_of(r, 2 * h + 1)];
            bf[cf] = fb.v;
        }

        // ---- stage kt+1 AFTER the reads (flight hides under MFMAs) ----
        if (nx) STAGE_TILE(slot ^ 1, kt + 1);

        __builtin_amdgcn_s_setprio(1);
        #pragma unroll
        for (int fi = 0; fi < 4; ++fi)
            #pragma unroll
            for (int cf = 0; cf < 2; ++cf)
                acc[fi][cf] = __builtin_amdgcn_mfma_scale_f32_32x32x64_f8f6f4(
                    af[fi], bf[cf], acc[fi][cf], 0, 0,
                    0, 0x7F7F7F7F, 0, 0x7F7F7F7F);   // fmt=fp8, scales=1.0
        __builtin_amdgcn_s_setprio(0);

        if (nx) {
            WAITVM0();      // drain stage(kt+1) after MFMA issue window
            BAR();
        }
        slot ^= 1;
    }
#undef STAGE_TILE

    // ---- epilogue ----
    // C/D 32x32 layout (m74/m101): col = lane&31, row = (v&3)+8*(v>>2)+4*(lane>>5)
    float cspart[2] = {0.0f, 0.0f};
    #pragma unroll
    for (int fi = 0; fi < 4; ++fi) {
        float rpart[16];
        #pragma unroll
        for (int v = 0; v < 16; ++v) rpart[v] = 0.0f;
        #pragma unroll
        for (int cf = 0; cf < 2; ++cf) {
            const int gcol = colBase + wn * 64 + cf * 32 + l31;
            #pragma unroll
            for (int v = 0; v < 16; ++v) {
                const int grow = rowBase + wm * 128 + fi * 32
                               + (v & 3) + 8 * (v >> 2) + 4 * h;
                const float tv = acc[fi][cf][v] * LOGIT_SCALE;
                if (gcol == grow + 1 && ((grow & 1) == 0)) {
                    tgt[grow] = tv; tgt[grow + 1] = tv;   // sim symmetric
                }
                const float ev = (gcol > grow) ? __expf(tv) : 0.0f;
                rpart[v] += ev;
                cspart[cf] += ev;
            }
        }
        // row sums: reduce over the 32 columns (lanes sharing l>>5)
        #pragma unroll
        for (int m = 1; m < 32; m <<= 1) {
            #pragma unroll
            for (int v = 0; v < 16; ++v) rpart[v] += __shfl_xor(rpart[v], m, 64);
        }
        if (l31 == 0) {
            float* dst = rs + (size_t)(jp * 4 + wn) * N_ROWS;
            #pragma unroll
            for (int v = 0; v < 16; ++v)
                dst[rowBase + wm * 128 + fi * 32 + (v & 3) + 8 * (v >> 2) + 4 * h]
                    = rpart[v];
        }
    }
    // column sums (mirror, incl. diag tiles): combine halves, lanes 0-31 write
    #pragma unroll
    for (int cf = 0; cf < 2; ++cf) {
        cspart[cf] += __shfl_xor(cspart[cf], 32, 64);
        if (lane < 32)
            cs[(size_t)(ip * 2 + wm) * N_ROWS + colBase + wn * 64 + cf * 32 + l31]
                = cspart[cf];
    }
}

// ------------- Kernel 3: per-row LSE - target logit --------------------------
// row x (panel P = x>>8): rs planes jp*4+{0..3} for jp >= P (tiles (P,jp));
// cs planes rt*2+{0,1} for rt <= P (tiles (rt,P), mirrored; diag included).
__global__ __launch_bounds__(256) void row_term_kernel(
    const float* __restrict__ rs, const float* __restrict__ cs,
    const float* __restrict__ tgt, float* __restrict__ terms)
{
    const int row = blockIdx.x * 256 + threadIdx.x;
    const int P = row >> 8;
    float s = 0.0f;
    for (int jp = P; jp < NPANEL; ++jp) {
        const float* b = rs + (size_t)(jp * 4) * N_ROWS + row;
        s += b[0] + b[N_ROWS] + b[2 * (size_t)N_ROWS] + b[3 * (size_t)N_ROWS];
    }
    for (int rt = 0; rt <= P; ++rt) {
        const float* b = cs + (size_t)(rt * 2) * N_ROWS + row;
        s += b[0] + b[N_ROWS];
    }
    terms[row] = logf(s) - tgt[row];
}

// ------------- Kernel 4: mean over rows --------------------------------------
__global__ __launch_bounds__(1024) void loss_kernel(
    const float* __restrict__ terms, float* __restrict__ out)
{
    const int t = threadIdx.x;
    float s = 0.0f;
    for (int i = t; i < N_ROWS; i += 1024) s += terms[i];
    #pragma unroll
    for (int m = 1; m < 64; m <<= 1) s += __shfl_xor(s, m, 64);
    __shared__ float red[16];
    if ((t & 63) == 0) red[t >> 6] = s;
    __syncthreads();
    if (t == 0) {
        float tot = 0.0f;
        #pragma unroll
        for (int i = 0; i < 16; ++i) tot += red[i];
        out[0] = tot * (1.0f / N_ROWS);
    }
}

extern "C" void kernel_launch(void* const* d_in, const int* in_sizes, int n_in,
                              void* d_out, int out_size, void* d_ws, size_t ws_size,
                              hipStream_t stream)
{
    const float* z_i = (const float*)d_in[0];
    const float* z_j = (const float*)d_in[1];
    float* out = (float*)d_out;

    // workspace layout
    unsigned char* xn8 = (unsigned char*)d_ws;                        // 8 MiB fp8
    float* rs    = (float*)(xn8 + (size_t)N_ROWS * DIMK);             // 4 MiB
    float* cs    = rs + (size_t)128 * N_ROWS;                         // 2 MiB
    float* tgt   = cs + (size_t)64 * N_ROWS;                          // 32 KiB
    float* terms = tgt + N_ROWS;                                      // 32 KiB

    norm_rows_kernel<<<N_ROWS / 4, 256, 0, stream>>>(z_i, z_j, (unsigned int*)xn8);
    simexp_kernel<<<NTILES, 512, 0, stream>>>(xn8, rs, cs, tgt);
    row_term_kernel<<<N_ROWS / 256, 256, 0, stream>>>(rs, cs, tgt, terms);
    loss_kernel<<<1, 1024, 0, stream>>>(terms, out);
}

// Round 15
// 87.769 us; speedup vs baseline: 4.9930x; 1.1323x over previous
//
#include <hip/hip_runtime.h>

// NT-Xent loss: z_i, z_j [4096,1024] f32 -> scalar f32 loss.
// loss = mean_i( log(sum_{j != i} exp(2*cos_sim(i,j))) - 2*cos_sim(i, i^1) )
//
// R15: simexp reverted to R12 byte-identical (best clean point, 71.3us:
//      MX-fp8 32x32x64, 256x128 triangle tiles, 2 slots 48KB, 2 blk/CU,
//      R11 body order). R14 proved 1-blk/CU 256^2 loses the cross-block
//      overlap (-5.5us); 3-slot/BK=128 variants hit the AGPR-spill pathology
//      (VGPR 128 signature). Tail trims: float4 loss loads, unrolled row_term.

#define N_ROWS 8192
#define HALF_N 4096
#define DIMK   1024
#define KTILES 16          // 1024 / 64
#define NJC    64          // 128-wide column panels
#define NTILES 1056        // sum_{jc} (jc/2 + 1)
#define LOGIT_SCALE (2.0f / 256.0f)   // /TEMPERATURE, undo 16*16 fp8 pre-scale

typedef float        f32x16 __attribute__((ext_vector_type(16)));
typedef int          i32x8  __attribute__((ext_vector_type(8)));
typedef unsigned int u32x4  __attribute__((ext_vector_type(4)));

// ---------------- fp8 e4m3 (OCP) conversion ---------------------------------
__device__ __forceinline__ unsigned int f32_to_e4m3_sw(float f) {
    unsigned int b = __float_as_uint(f);
    unsigned int s = (b >> 24) & 0x80u;
    float a = fabsf(f);
    if (a < 0.0009765625f) return s;
    if (a < 0.015625f) {
        int q = (int)rintf(a * 512.0f);
        return s | (unsigned int)q;
    }
    if (a >= 464.0f) return s | 0x7Eu;
    int e = (int)((b >> 23) & 0xFF) - 127;
    unsigned int man = b & 0x7FFFFFu;
    unsigned int r = man + 0x7FFFFu + ((man >> 20) & 1u);
    unsigned int m8 = r >> 20;
    if (m8 == 8u) { m8 = 0u; ++e; if (e > 8) return s | 0x7Eu; }
    return s | ((unsigned int)(e + 7) << 3) | m8;
}

__device__ __forceinline__ unsigned int pack4_e4m3(float x, float y,
                                                   float z, float w) {
#if __has_builtin(__builtin_amdgcn_cvt_pk_fp8_f32)
    int p = __builtin_amdgcn_cvt_pk_fp8_f32(x, y, 0, false);   // low word
    p     = __builtin_amdgcn_cvt_pk_fp8_f32(z, w, p, true);    // high word
    return (unsigned int)p;
#else
    return f32_to_e4m3_sw(x) | (f32_to_e4m3_sw(y) << 8)
         | (f32_to_e4m3_sw(z) << 16) | (f32_to_e4m3_sw(w) << 24);
#endif
}

// ---------------- Kernel 1: row L2-normalize, f32 -> fp8*16 ------------------
__global__ __launch_bounds__(256) void norm_rows_kernel(
    const float* __restrict__ z_i, const float* __restrict__ z_j,
    unsigned int* __restrict__ xn8)   // [8192][256] u32 (=1024 fp8)
{
    const int wave = threadIdx.x >> 6, lane = threadIdx.x & 63;
    const int row = blockIdx.x * 4 + wave;
    const float* src = (row < HALF_N) ? (z_i + (size_t)row * DIMK)
                                      : (z_j + (size_t)(row - HALF_N) * DIMK);
    float4 v[4];
    float ss = 0.0f;
    #pragma unroll
    for (int i = 0; i < 4; ++i) {
        v[i] = ((const float4*)src)[i * 64 + lane];
        ss += v[i].x * v[i].x + v[i].y * v[i].y + v[i].z * v[i].z + v[i].w * v[i].w;
    }
    #pragma unroll
    for (int m = 1; m < 64; m <<= 1) ss += __shfl_xor(ss, m, 64);
    const float rn = 16.0f / fmaxf(sqrtf(ss), 1e-8f);   // x16 fp8 pre-scale

    unsigned int* dst = xn8 + (size_t)row * (DIMK / 4);
    #pragma unroll
    for (int i = 0; i < 4; ++i)
        dst[i * 64 + lane] = pack4_e4m3(v[i].x * rn, v[i].y * rn,
                                        v[i].z * rn, v[i].w * rn);
}

// ---- Kernel 2: fused sim-GEMM (MX-fp8 32x32x64) + exp row/col sums ----------
#define BAR() do { asm volatile("" ::: "memory"); \
                   __builtin_amdgcn_s_barrier();  \
                   asm volatile("" ::: "memory"); } while (0)
#define WAITVM0() asm volatile("s_waitcnt vmcnt(0)" ::: "memory")
#define GLDS(gp, lp) __builtin_amdgcn_global_load_lds(                          \
        (const __attribute__((address_space(1))) void*)(gp),                    \
        (__attribute__((address_space(3))) void*)(lp), 16, 0, 0)

// LDS placement (R9): pair two 64-B rows into a 128-B window, XOR chunk pos:
// unit(r,c) = (r>>1)*8 + ((((r&1)<<2)|c) ^ ((r>>1)&7)). Bijective; frag reads
// phase-uniform; GLDS sources = 64-B coalesced segments.
__device__ __forceinline__ int unit_of(int r, int c) {
    return ((r >> 1) << 3) + (((((r & 1) << 2) | c)) ^ ((r >> 1) & 7));
}

__global__ __launch_bounds__(256, 2) void simexp_kernel(
    const unsigned char* __restrict__ xn8,
    float* __restrict__ rs,     // [128][N_ROWS] planes: jc*2 + wn
    float* __restrict__ cs,     // [64][N_ROWS]  planes: rt*2 + wm
    float* __restrict__ tgt)    // [N_ROWS]
{
    __shared__ u32x4 Abuf[2][1024];   // 2 x 16 KiB (256 rows x 4 chunks)
    __shared__ u32x4 Bbuf[2][512];    // 2 x  8 KiB (128 rows x 4 chunks)

    // bijective XCD swizzle: 1056 = 8 * 132
    const int orig = blockIdx.x;
    const int bid  = (orig & 7) * 132 + (orig >> 3);

    // decode (rt, jc): tiles ordered jc-major, rt = 0..jc/2
    int rem = bid, jc = 0;
    for (;;) { const int cnt = (jc >> 1) + 1; if (rem < cnt) break; rem -= cnt; ++jc; }
    const int rt = rem;

    const int t = threadIdx.x;
    const int lane = t & 63, wave = t >> 6;
    const int wm = wave >> 1, wn = wave & 1;     // 2x2 wave grid
    const int rowBase = rt * 256, colBase = jc * 128;
    const int l31 = lane & 31, h = lane >> 5;

    f32x16 acc[4][2];
    #pragma unroll
    for (int i = 0; i < 4; ++i)
        #pragma unroll
        for (int j = 0; j < 2; ++j)
            #pragma unroll
            for (int v = 0; v < 16; ++v) acc[i][j][v] = 0.0f;

    // staging: unit u = s_*256 + t (linear LDS dest); inverse map:
    // r2 = u>>3, y = (u&7) ^ (r2&7), row = 2*r2 + (y>>2), chunk = y&3.
#define STAGE_TILE(SLOT, KT) do {                                                \
        _Pragma("unroll")                                                        \
        for (int s_ = 0; s_ < 4; ++s_) {                                         \
            const int u_  = s_ * 256 + t;                                        \
            const int r2_ = u_ >> 3;                                             \
            const int y_  = (u_ & 7) ^ (r2_ & 7);                                \
            const int rl_ = 2 * r2_ + (y_ >> 2);                                 \
            const unsigned char* g = xn8 +                                       \
                (size_t)(rowBase + rl_) * DIMK + (KT) * 64 + (y_ & 3) * 16;      \
            GLDS(g, &Abuf[SLOT][s_ * 256 + wave * 64]);                          \
        }                                                                        \
        _Pragma("unroll")                                                        \
        for (int s_ = 0; s_ < 2; ++s_) {                                         \
            const int u_  = s_ * 256 + t;                                        \
            const int r2_ = u_ >> 3;                                             \
            const int y_  = (u_ & 7) ^ (r2_ & 7);                                \
            const int rl_ = 2 * r2_ + (y_ >> 2);                                 \
            const unsigned char* g = xn8 +                                       \
                (size_t)(colBase + rl_) * DIMK + (KT) * 64 + (y_ & 3) * 16;      \
            GLDS(g, &Bbuf[SLOT][s_ * 256 + wave * 64]);                          \
        }                                                                        \
    } while (0)

    // prologue: tile 0 into slot 0
    STAGE_TILE(0, 0);
    WAITVM0();
    BAR();

    int slot = 0;
    for (int kt = 0; kt < KTILES; ++kt) {
        const bool nx = (kt + 1 < KTILES);

        // ---- frag reads FIRST (vmcnt already 0 here -> no forced drain) ----
        union Frag { u32x4 q[2]; i32x8 v; };
        i32x8 af[4], bf[2];
        #pragma unroll
        for (int fi = 0; fi < 4; ++fi) {
            const int r = wm * 128 + fi * 32 + l31;
            Frag fa;
            fa.q[0] = Abuf[slot][unit_of(r, 2 * h)];
            fa.q[1] = Abuf[slot][unit_of(r, 2 * h + 1)];
            af[fi] = fa.v;
        }
        #pragma unroll
        for (int cf = 0; cf < 2; ++cf) {
            const int r = wn * 64 + cf * 32 + l31;
            Frag fb;
            fb.q[0] = Bbuf[slot][unit_of(r, 2 * h)];
            fb.q[1] = Bbuf[slot][unit_of(r, 2 * h + 1)];
            bf[cf] = fb.v;
        }

        // ---- stage kt+1 AFTER the reads (flight hides under MFMAs) ----
        if (nx) STAGE_TILE(slot ^ 1, kt + 1);

        __builtin_amdgcn_s_setprio(1);
        #pragma unroll
        for (int fi = 0; fi < 4; ++fi)
            #pragma unroll
            for (int cf = 0; cf < 2; ++cf)
                acc[fi][cf] = __builtin_amdgcn_mfma_scale_f32_32x32x64_f8f6f4(
                    af[fi], bf[cf], acc[fi][cf], 0, 0,
                    0, 0x7F7F7F7F, 0, 0x7F7F7F7F);   // fmt=fp8, scales=1.0
        __builtin_amdgcn_s_setprio(0);

        if (nx) {
            WAITVM0();      // drain stage(kt+1) after MFMA issue window
            BAR();
        }
        slot ^= 1;
    }
#undef STAGE_TILE

    // ---- epilogue ----
    // C/D 32x32 layout (m74/m101): col = lane&31, row = (v&3)+8*(v>>2)+4*(lane>>5)
    float cspart[2] = {0.0f, 0.0f};
    #pragma unroll
    for (int fi = 0; fi < 4; ++fi) {
        float rpart[16];
        #pragma unroll
        for (int v = 0; v < 16; ++v) rpart[v] = 0.0f;
        #pragma unroll
        for (int cf = 0; cf < 2; ++cf) {
            const int gcol = colBase + wn * 64 + cf * 32 + l31;
            #pragma unroll
            for (int v = 0; v < 16; ++v) {
                const int grow = rowBase + wm * 128 + fi * 32
                               + (v & 3) + 8 * (v >> 2) + 4 * h;
                const float tv = acc[fi][cf][v] * LOGIT_SCALE;
                if (gcol == grow + 1 && ((grow & 1) == 0)) {
                    tgt[grow] = tv; tgt[grow + 1] = tv;   // sim symmetric
                }
                const float ev = (gcol > grow) ? __expf(tv) : 0.0f;
                rpart[v] += ev;
                cspart[cf] += ev;
            }
        }
        // row sums: reduce over the 32 columns (lanes sharing l>>5)
        #pragma unroll
        for (int m = 1; m < 32; m <<= 1) {
            #pragma unroll
            for (int v = 0; v < 16; ++v) rpart[v] += __shfl_xor(rpart[v], m, 64);
        }
        if (l31 == 0) {
            float* dst = rs + (size_t)(jc * 2 + wn) * N_ROWS;
            #pragma unroll
            for (int v = 0; v < 16; ++v)
                dst[rowBase + wm * 128 + fi * 32 + (v & 3) + 8 * (v >> 2) + 4 * h]
                    = rpart[v];
        }
    }
    // column sums (mirror): combine lane halves, lanes 0-31 write
    #pragma unroll
    for (int cf = 0; cf < 2; ++cf) {
        cspart[cf] += __shfl_xor(cspart[cf], 32, 64);
        if (lane < 32)
            cs[(size_t)(rt * 2 + wm) * N_ROWS + colBase + wn * 64 + cf * 32 + l31]
                = cspart[cf];
    }
}

// ------------- Kernel 3: per-row LSE - target logit --------------------------
// row x: rs planes jc*2+{0,1} for jc >= 2*(x>>8); cs planes rt*2+{0,1} for
// rt <= (x>>7)/2  (exactly the tiles that exist for this row/col).
__global__ __launch_bounds__(256) void row_term_kernel(
    const float* __restrict__ rs, const float* __restrict__ cs,
    const float* __restrict__ tgt, float* __restrict__ terms)
{
    const int row = blockIdx.x * 256 + threadIdx.x;
    const int P = row >> 8, jcx = row >> 7;
    float s = 0.0f;
    #pragma unroll 4
    for (int jc = 2 * P; jc < NJC; ++jc) {
        const float* b = rs + (size_t)(jc * 2) * N_ROWS + row;
        s += b[0] + b[N_ROWS];
    }
    #pragma unroll 4
    for (int rt = 0; rt <= (jcx >> 1); ++rt) {
        const float* b = cs + (size_t)(rt * 2) * N_ROWS + row;
        s += b[0] + b[N_ROWS];
    }
    terms[row] = logf(s) - tgt[row];
}

// ------------- Kernel 4: mean over rows --------------------------------------
__global__ __launch_bounds__(1024) void loss_kernel(
    const float* __restrict__ terms, float* __restrict__ out)
{
    const int t = threadIdx.x;
    const float4* t4 = (const float4*)terms;
    float s = 0.0f;
    #pragma unroll
    for (int i = 0; i < 2; ++i) {
        const float4 v = t4[i * 1024 + t];
        s += v.x + v.y + v.z + v.w;
    }
    #pragma unroll
    for (int m = 1; m < 64; m <<= 1) s += __shfl_xor(s, m, 64);
    __shared__ float red[16];
    if ((t & 63) == 0) red[t >> 6] = s;
    __syncthreads();
    if (t == 0) {
        float tot = 0.0f;
        #pragma unroll
        for (int i = 0; i < 16; ++i) tot += red[i];
        out[0] = tot * (1.0f / N_ROWS);
    }
}

extern "C" void kernel_launch(void* const* d_in, const int* in_sizes, int n_in,
                              void* d_out, int out_size, void* d_ws, size_t ws_size,
                              hipStream_t stream)
{
    const float* z_i = (const float*)d_in[0];
    const float* z_j = (const float*)d_in[1];
    float* out = (float*)d_out;

    // workspace layout
    unsigned char* xn8 = (unsigned char*)d_ws;                        // 8 MiB fp8
    float* rs    = (float*)(xn8 + (size_t)N_ROWS * DIMK);             // 4 MiB
    float* cs    = rs + (size_t)128 * N_ROWS;                         // 2 MiB
    float* tgt   = cs + (size_t)64 * N_ROWS;                          // 32 KiB
    float* terms = tgt + N_ROWS;                                      // 32 KiB

    norm_rows_kernel<<<N_ROWS / 4, 256, 0, stream>>>(z_i, z_j, (unsigned int*)xn8);
    simexp_kernel<<<NTILES, 256, 0, stream>>>(xn8, rs, cs, tgt);
    row_term_kernel<<<N_ROWS / 256, 256, 0, stream>>>(rs, cs, tgt, terms);
    loss_kernel<<<1, 1024, 0, stream>>>(terms, out);
}

// Round 16
// 87.507 us; speedup vs baseline: 5.0080x; 1.0030x over previous
//
#include <hip/hip_runtime.h>

// NT-Xent loss: z_i, z_j [4096,1024] f32 -> scalar f32 loss.
// loss = mean_i( log(sum_{j != i} exp(2*cos_sim(i,j))) - 2*cos_sim(i, i^1) )
//
// R16: simexp byte-identical to R12/R15 (4x-verified 71.3us clean point).
//      Tail consolidation: row_term fuses the block-level mean reduction
//      (terms array eliminated); loss_kernel folds 32 partials with 1 wave;
//      norm_rows uses 8-wave blocks.

#define N_ROWS 8192
#define HALF_N 4096
#define DIMK   1024
#define KTILES 16          // 1024 / 64
#define NJC    64          // 128-wide column panels
#define NTILES 1056        // sum_{jc} (jc/2 + 1)
#define LOGIT_SCALE (2.0f / 256.0f)   // /TEMPERATURE, undo 16*16 fp8 pre-scale

typedef float        f32x16 __attribute__((ext_vector_type(16)));
typedef int          i32x8  __attribute__((ext_vector_type(8)));
typedef unsigned int u32x4  __attribute__((ext_vector_type(4)));

// ---------------- fp8 e4m3 (OCP) conversion ---------------------------------
__device__ __forceinline__ unsigned int f32_to_e4m3_sw(float f) {
    unsigned int b = __float_as_uint(f);
    unsigned int s = (b >> 24) & 0x80u;
    float a = fabsf(f);
    if (a < 0.0009765625f) return s;
    if (a < 0.015625f) {
        int q = (int)rintf(a * 512.0f);
        return s | (unsigned int)q;
    }
    if (a >= 464.0f) return s | 0x7Eu;
    int e = (int)((b >> 23) & 0xFF) - 127;
    unsigned int man = b & 0x7FFFFFu;
    unsigned int r = man + 0x7FFFFu + ((man >> 20) & 1u);
    unsigned int m8 = r >> 20;
    if (m8 == 8u) { m8 = 0u; ++e; if (e > 8) return s | 0x7Eu; }
    return s | ((unsigned int)(e + 7) << 3) | m8;
}

__device__ __forceinline__ unsigned int pack4_e4m3(float x, float y,
                                                   float z, float w) {
#if __has_builtin(__builtin_amdgcn_cvt_pk_fp8_f32)
    int p = __builtin_amdgcn_cvt_pk_fp8_f32(x, y, 0, false);   // low word
    p     = __builtin_amdgcn_cvt_pk_fp8_f32(z, w, p, true);    // high word
    return (unsigned int)p;
#else
    return f32_to_e4m3_sw(x) | (f32_to_e4m3_sw(y) << 8)
         | (f32_to_e4m3_sw(z) << 16) | (f32_to_e4m3_sw(w) << 24);
#endif
}

// ---------------- Kernel 1: row L2-normalize, f32 -> fp8*16 ------------------
// one wave per row; 8 waves per block
__global__ __launch_bounds__(512) void norm_rows_kernel(
    const float* __restrict__ z_i, const float* __restrict__ z_j,
    unsigned int* __restrict__ xn8)   // [8192][256] u32 (=1024 fp8)
{
    const int wave = threadIdx.x >> 6, lane = threadIdx.x & 63;
    const int row = blockIdx.x * 8 + wave;
    const float* src = (row < HALF_N) ? (z_i + (size_t)row * DIMK)
                                      : (z_j + (size_t)(row - HALF_N) * DIMK);
    float4 v[4];
    float ss = 0.0f;
    #pragma unroll
    for (int i = 0; i < 4; ++i) {
        v[i] = ((const float4*)src)[i * 64 + lane];
        ss += v[i].x * v[i].x + v[i].y * v[i].y + v[i].z * v[i].z + v[i].w * v[i].w;
    }
    #pragma unroll
    for (int m = 1; m < 64; m <<= 1) ss += __shfl_xor(ss, m, 64);
    const float rn = 16.0f / fmaxf(sqrtf(ss), 1e-8f);   // x16 fp8 pre-scale

    unsigned int* dst = xn8 + (size_t)row * (DIMK / 4);
    #pragma unroll
    for (int i = 0; i < 4; ++i)
        dst[i * 64 + lane] = pack4_e4m3(v[i].x * rn, v[i].y * rn,
                                        v[i].z * rn, v[i].w * rn);
}

// ---- Kernel 2: fused sim-GEMM (MX-fp8 32x32x64) + exp row/col sums ----------
#define BAR() do { asm volatile("" ::: "memory"); \
                   __builtin_amdgcn_s_barrier();  \
                   asm volatile("" ::: "memory"); } while (0)
#define WAITVM0() asm volatile("s_waitcnt vmcnt(0)" ::: "memory")
#define GLDS(gp, lp) __builtin_amdgcn_global_load_lds(                          \
        (const __attribute__((address_space(1))) void*)(gp),                    \
        (__attribute__((address_space(3))) void*)(lp), 16, 0, 0)

// LDS placement (R9): pair two 64-B rows into a 128-B window, XOR chunk pos:
// unit(r,c) = (r>>1)*8 + ((((r&1)<<2)|c) ^ ((r>>1)&7)). Bijective; frag reads
// phase-uniform; GLDS sources = 64-B coalesced segments.
__device__ __forceinline__ int unit_of(int r, int c) {
    return ((r >> 1) << 3) + (((((r & 1) << 2) | c)) ^ ((r >> 1) & 7));
}

__global__ __launch_bounds__(256, 2) void simexp_kernel(
    const unsigned char* __restrict__ xn8,
    float* __restrict__ rs,     // [128][N_ROWS] planes: jc*2 + wn
    float* __restrict__ cs,     // [64][N_ROWS]  planes: rt*2 + wm
    float* __restrict__ tgt)    // [N_ROWS]
{
    __shared__ u32x4 Abuf[2][1024];   // 2 x 16 KiB (256 rows x 4 chunks)
    __shared__ u32x4 Bbuf[2][512];    // 2 x  8 KiB (128 rows x 4 chunks)

    // bijective XCD swizzle: 1056 = 8 * 132
    const int orig = blockIdx.x;
    const int bid  = (orig & 7) * 132 + (orig >> 3);

    // decode (rt, jc): tiles ordered jc-major, rt = 0..jc/2
    int rem = bid, jc = 0;
    for (;;) { const int cnt = (jc >> 1) + 1; if (rem < cnt) break; rem -= cnt; ++jc; }
    const int rt = rem;

    const int t = threadIdx.x;
    const int lane = t & 63, wave = t >> 6;
    const int wm = wave >> 1, wn = wave & 1;     // 2x2 wave grid
    const int rowBase = rt * 256, colBase = jc * 128;
    const int l31 = lane & 31, h = lane >> 5;

    f32x16 acc[4][2];
    #pragma unroll
    for (int i = 0; i < 4; ++i)
        #pragma unroll
        for (int j = 0; j < 2; ++j)
            #pragma unroll
            for (int v = 0; v < 16; ++v) acc[i][j][v] = 0.0f;

    // staging: unit u = s_*256 + t (linear LDS dest); inverse map:
    // r2 = u>>3, y = (u&7) ^ (r2&7), row = 2*r2 + (y>>2), chunk = y&3.
#define STAGE_TILE(SLOT, KT) do {                                                \
        _Pragma("unroll")                                                        \
        for (int s_ = 0; s_ < 4; ++s_) {                                         \
            const int u_  = s_ * 256 + t;                                        \
            const int r2_ = u_ >> 3;                                             \
            const int y_  = (u_ & 7) ^ (r2_ & 7);                                \
            const int rl_ = 2 * r2_ + (y_ >> 2);                                 \
            const unsigned char* g = xn8 +                                       \
                (size_t)(rowBase + rl_) * DIMK + (KT) * 64 + (y_ & 3) * 16;      \
            GLDS(g, &Abuf[SLOT][s_ * 256 + wave * 64]);                          \
        }                                                                        \
        _Pragma("unroll")                                                        \
        for (int s_ = 0; s_ < 2; ++s_) {                                         \
            const int u_  = s_ * 256 + t;                                        \
            const int r2_ = u_ >> 3;                                             \
            const int y_  = (u_ & 7) ^ (r2_ & 7);                                \
            const int rl_ = 2 * r2_ + (y_ >> 2);                                 \
            const unsigned char* g = xn8 +                                       \
                (size_t)(colBase + rl_) * DIMK + (KT) * 64 + (y_ & 3) * 16;      \
            GLDS(g, &Bbuf[SLOT][s_ * 256 + wave * 64]);                          \
        }                                                                        \
    } while (0)

    // prologue: tile 0 into slot 0
    STAGE_TILE(0, 0);
    WAITVM0();
    BAR();

    int slot = 0;
    for (int kt = 0; kt < KTILES; ++kt) {
        const bool nx = (kt + 1 < KTILES);

        // ---- frag reads FIRST (vmcnt already 0 here -> no forced drain) ----
        union Frag { u32x4 q[2]; i32x8 v; };
        i32x8 af[4], bf[2];
        #pragma unroll
        for (int fi = 0; fi < 4; ++fi) {
            const int r = wm * 128 + fi * 32 + l31;
            Frag fa;
            fa.q[0] = Abuf[slot][unit_of(r, 2 * h)];
            fa.q[1] = Abuf[slot][unit_of(r, 2 * h + 1)];
            af[fi] = fa.v;
        }
        #pragma unroll
        for (int cf = 0; cf < 2; ++cf) {
            const int r = wn * 64 + cf * 32 + l31;
            Frag fb;
            fb.q[0] = Bbuf[slot][unit_of(r, 2 * h)];
            fb.q[1] = Bbuf[slot][unit_of(r, 2 * h + 1)];
            bf[cf] = fb.v;
        }

        // ---- stage kt+1 AFTER the reads (flight hides under MFMAs) ----
        if (nx) STAGE_TILE(slot ^ 1, kt + 1);

        __builtin_amdgcn_s_setprio(1);
        #pragma unroll
        for (int fi = 0; fi < 4; ++fi)
            #pragma unroll
            for (int cf = 0; cf < 2; ++cf)
                acc[fi][cf] = __builtin_amdgcn_mfma_scale_f32_32x32x64_f8f6f4(
                    af[fi], bf[cf], acc[fi][cf], 0, 0,
                    0, 0x7F7F7F7F, 0, 0x7F7F7F7F);   // fmt=fp8, scales=1.0
        __builtin_amdgcn_s_setprio(0);

        if (nx) {
            WAITVM0();      // drain stage(kt+1) after MFMA issue window
            BAR();
        }
        slot ^= 1;
    }
#undef STAGE_TILE

    // ---- epilogue ----
    // C/D 32x32 layout (m74/m101): col = lane&31, row = (v&3)+8*(v>>2)+4*(lane>>5)
    float cspart[2] = {0.0f, 0.0f};
    #pragma unroll
    for (int fi = 0; fi < 4; ++fi) {
        float rpart[16];
        #pragma unroll
        for (int v = 0; v < 16; ++v) rpart[v] = 0.0f;
        #pragma unroll
        for (int cf = 0; cf < 2; ++cf) {
            const int gcol = colBase + wn * 64 + cf * 32 + l31;
            #pragma unroll
            for (int v = 0; v < 16; ++v) {
                const int grow = rowBase + wm * 128 + fi * 32
                               + (v & 3) + 8 * (v >> 2) + 4 * h;
                const float tv = acc[fi][cf][v] * LOGIT_SCALE;
                if (gcol == grow + 1 && ((grow & 1) == 0)) {
                    tgt[grow] = tv; tgt[grow + 1] = tv;   // sim symmetric
                }
                const float ev = (gcol > grow) ? __expf(tv) : 0.0f;
                rpart[v] += ev;
                cspart[cf] += ev;
            }
        }
        // row sums: reduce over the 32 columns (lanes sharing l>>5)
        #pragma unroll
        for (int m = 1; m < 32; m <<= 1) {
            #pragma unroll
            for (int v = 0; v < 16; ++v) rpart[v] += __shfl_xor(rpart[v], m, 64);
        }
        if (l31 == 0) {
            float* dst = rs + (size_t)(jc * 2 + wn) * N_ROWS;
            #pragma unroll
            for (int v = 0; v < 16; ++v)
                dst[rowBase + wm * 128 + fi * 32 + (v & 3) + 8 * (v >> 2) + 4 * h]
                    = rpart[v];
        }
    }
    // column sums (mirror): combine lane halves, lanes 0-31 write
    #pragma unroll
    for (int cf = 0; cf < 2; ++cf) {
        cspart[cf] += __shfl_xor(cspart[cf], 32, 64);
        if (lane < 32)
            cs[(size_t)(rt * 2 + wm) * N_ROWS + colBase + wn * 64 + cf * 32 + l31]
                = cspart[cf];
    }
}

// ------------- Kernel 3: per-row LSE - target, fused block reduction ---------
// row x: rs planes jc*2+{0,1} for jc >= 2*(x>>8); cs planes rt*2+{0,1} for
// rt <= (x>>7)/2. Block-reduces its 256 terms into partial[blockIdx].
__global__ __launch_bounds__(256) void row_term_kernel(
    const float* __restrict__ rs, const float* __restrict__ cs,
    const float* __restrict__ tgt, float* __restrict__ partial)
{
    const int row = blockIdx.x * 256 + threadIdx.x;
    const int P = row >> 8, jcx = row >> 7;
    float s = 0.0f;
    #pragma unroll 4
    for (int jc = 2 * P; jc < NJC; ++jc) {
        const float* b = rs + (size_t)(jc * 2) * N_ROWS + row;
        s += b[0] + b[N_ROWS];
    }
    #pragma unroll 4
    for (int rt = 0; rt <= (jcx >> 1); ++rt) {
        const float* b = cs + (size_t)(rt * 2) * N_ROWS + row;
        s += b[0] + b[N_ROWS];
    }
    float term = logf(s) - tgt[row];
    // block reduction -> one partial per block
    #pragma unroll
    for (int m = 1; m < 64; m <<= 1) term += __shfl_xor(term, m, 64);
    __shared__ float red[4];
    const int lane = threadIdx.x & 63, wave = threadIdx.x >> 6;
    if (lane == 0) red[wave] = term;
    __syncthreads();
    if (threadIdx.x == 0)
        partial[blockIdx.x] = red[0] + red[1] + red[2] + red[3];
}

// ------------- Kernel 4: fold 32 partials -> mean ----------------------------
__global__ __launch_bounds__(64) void loss_kernel(
    const float* __restrict__ partial, float* __restrict__ out)
{
    const int t = threadIdx.x;
    float s = (t < N_ROWS / 256) ? partial[t] : 0.0f;
    #pragma unroll
    for (int m = 1; m < 64; m <<= 1) s += __shfl_xor(s, m, 64);
    if (t == 0) out[0] = s * (1.0f / N_ROWS);
}

extern "C" void kernel_launch(void* const* d_in, const int* in_sizes, int n_in,
                              void* d_out, int out_size, void* d_ws, size_t ws_size,
                              hipStream_t stream)
{
    const float* z_i = (const float*)d_in[0];
    const float* z_j = (const float*)d_in[1];
    float* out = (float*)d_out;

    // workspace layout
    unsigned char* xn8 = (unsigned char*)d_ws;                        // 8 MiB fp8
    float* rs      = (float*)(xn8 + (size_t)N_ROWS * DIMK);           // 4 MiB
    float* cs      = rs + (size_t)128 * N_ROWS;                       // 2 MiB
    float* tgt     = cs + (size_t)64 * N_ROWS;                        // 32 KiB
    float* partial = tgt + N_ROWS;                                    // 128 B

    norm_rows_kernel<<<N_ROWS / 8, 512, 0, stream>>>(z_i, z_j, (unsigned int*)xn8);
    simexp_kernel<<<NTILES, 256, 0, stream>>>(xn8, rs, cs, tgt);
    row_term_kernel<<<N_ROWS / 256, 256, 0, stream>>>(rs, cs, tgt, partial);
    loss_kernel<<<1, 64, 0, stream>>>(partial, out);
}